// Round 4
// baseline (584.557 us; speedup 1.0000x reference)
//
#include <hip/hip_runtime.h>
#include <hip/hip_bf16.h>
#include <stdint.h>

#define N_NODES 50000
#define N_EDGES 500000
#define NODE_IN 128
#define EDGE_IN 64
#define HID 128
#define K_H1 384   // 3*HID
#define N_H1 512   // 4*HID
#define N_H2 256   // 2*HID

#define EPB 64     // edges per block -> 2 independent blocks/CU (round-3 lesson:
                   // 1 block/CU lockstep-convoys on barriers; keep 2 blocks)

typedef short s8v __attribute__((ext_vector_type(8)));   // 8 x bf16 bits (4 VGPR)
typedef float f4v __attribute__((ext_vector_type(4)));   // MFMA accumulator

// HW packed fp32->bf16 (v_cvt_pk_bf16_f32): low 16 bits = a, high = b
__device__ __forceinline__ unsigned int pk_bf16(float a, float b) {
    union { __hip_bfloat162 h; unsigned int u; } c;
    c.h = __float22bfloat162_rn(float2{a, b});
    return c.u;
}

// Load 8 consecutive fp32 from global, convert to a bf16 fragment.
// Fragment map (A and B identical): lane(lm,quad) holds [other=lm][k=quad*8+j].
__device__ __forceinline__ s8v load_a_f32(const float* __restrict__ base, int row, int ld, int koff) {
    const float4* p = (const float4*)(base + row * ld + koff);
    float4 x0 = p[0];
    float4 x1 = p[1];
    union { s8v v; unsigned int u[4]; } r;
    r.u[0] = pk_bf16(x0.x, x0.y);
    r.u[1] = pk_bf16(x0.z, x0.w);
    r.u[2] = pk_bf16(x1.x, x1.y);
    r.u[3] = pk_bf16(x1.z, x1.w);
    return r.v;
}

// Pack W (KxN row-major fp32) into fragment-ordered bf16:
// dst[(((kb*(N/16) + nt)*64 + lane)*8 + j] = W[kb*32 + (lane>>4)*8 + j][nt*16 + (lane&15)]
// Serves as B-frag for D=X@W, and as A-frag (=W^T) for the swapped D=W^T@X^T.
__device__ __forceinline__ void pack_one(const float* __restrict__ src, unsigned short* __restrict__ dst,
                                         int idx, int N) {
    int j = idx & 7;
    int lane = (idx >> 3) & 63;
    int rest = idx >> 9;
    int NT = N >> 4;
    int nt = rest % NT;
    int kb = rest / NT;
    int n = nt * 16 + (lane & 15);
    int k = kb * 32 + ((lane >> 4) << 3) + j;
    union { __hip_bfloat16 h; unsigned short s; } c;
    c.h = __float2bfloat16(src[k * N + n]);
    dst[idx] = c.s;
}

#define WN_ELEMS (NODE_IN * HID)          // 16384
#define WE_ELEMS (EDGE_IN * HID)          // 8192
#define W1_ELEMS (K_H1 * N_H1)            // 196608
#define W2_ELEMS (N_H1 * N_H2)            // 131072
#define PACK_TOTAL (WN_ELEMS + WE_ELEMS + W1_ELEMS + W2_ELEMS)

__global__ void pack_all(const float* __restrict__ Wn, const float* __restrict__ We,
                         const float* __restrict__ W1, const float* __restrict__ W2,
                         unsigned short* __restrict__ Wnp, unsigned short* __restrict__ Wep,
                         unsigned short* __restrict__ W1p, unsigned short* __restrict__ W2p) {
    int idx = blockIdx.x * blockDim.x + threadIdx.x;
    if (idx >= PACK_TOTAL) return;
    if (idx < WN_ELEMS) { pack_one(Wn, Wnp, idx, HID); return; }
    idx -= WN_ELEMS;
    if (idx < WE_ELEMS) { pack_one(We, Wep, idx, HID); return; }
    idx -= WE_ELEMS;
    if (idx < W1_ELEMS) { pack_one(W1, W1p, idx, N_H1); return; }
    idx -= W1_ELEMS;
    pack_one(W2, W2p, idx, N_H2);
}

// node_f^T formulation: D[m=hidcol][n=node] = Wn^T @ x^T.
// block: 256 threads (4 waves), 64 nodes; wave w owns node-tile nt=w, all 8 m-tiles.
__global__ __launch_bounds__(256, 4) void node_feat_kernel(
    const float* __restrict__ x, const unsigned short* __restrict__ Wnp,
    const float* __restrict__ bn, unsigned short* __restrict__ node_f)
{
    int tid = threadIdx.x;
    int wave = tid >> 6, lane = tid & 63;
    int lm = lane & 15, quad = lane >> 4;
    int row0 = blockIdx.x * 64;
    int node = row0 + wave * 16 + lm;
    int nodec = node < N_NODES ? node : N_NODES - 1;

    f4v zero = {0.f, 0.f, 0.f, 0.f};
    f4v acc[8];
    #pragma unroll
    for (int mt = 0; mt < 8; ++mt) acc[mt] = zero;

    for (int kb = 0; kb < 4; ++kb) {
        s8v b = load_a_f32(x, nodec, NODE_IN, kb * 32 + quad * 8);
        #pragma unroll
        for (int mt = 0; mt < 8; ++mt) {
            s8v a = *(const s8v*)(Wnp + (((kb * 8 + mt) * 64 + lane) << 3));
            acc[mt] = __builtin_amdgcn_mfma_f32_16x16x32_bf16(a, b, acc[mt], 0, 0, 0);
        }
    }

    if (node < N_NODES) {
        #pragma unroll
        for (int mt = 0; mt < 8; ++mt) {
            float4 bv = *(const float4*)(bn + mt * 16 + quad * 4);
            uint2 pk;
            pk.x = pk_bf16(fmaxf(acc[mt][0] + bv.x, 0.f), fmaxf(acc[mt][1] + bv.y, 0.f));
            pk.y = pk_bf16(fmaxf(acc[mt][2] + bv.z, 0.f), fmaxf(acc[mt][3] + bv.w, 0.f));
            *(uint2*)(node_f + node * HID + mt * 16 + quad * 4) = pk;
        }
    }
}

// Fused per-edge pipeline (all GEMMs in swapped D=W^T@X^T form).
// block: 512 threads (8 waves), 64 edges. LDS ~66.8 KB -> 2 blocks/CU.
//
// REGISTER BUDGET (the binding constraint):
// __launch_bounds__(512,4) = 128 unified VGPR+AGPR. Phase 2: acc1[4][4] =
// 64 AGPR; round-2 measured arch VGPR = 52 -> ~12 spare. A full anx[4]
// prefetch (+16) spilled (rounds 0-1: 360-486 MB scratch). This version
// uses a SPLIT rotation costing only +8 regs for a full 1-kb-ahead weight
// prefetch: anx[2] (t=0,1) loaded before the MFMA burst; afr[2],afr[3] for
// kb+1 loaded after the burst into the just-freed registers. Phase 3 has
// headroom (acc1 dead) -> full bnx[4]+anx[2] rotation (~90 live regs).
// Spill tripwire: WRITE_SIZE must stay ~2 MB; arch VGPR must stay <= 64.
#define CSTR 392   // comb row stride (shorts, 384 + 8 pad)
#define H1STR 520  // h1 row stride (shorts, 512 + 8 pad)

__global__ __launch_bounds__(512, 4) void fused_edge_kernel(
    const int* __restrict__ edge_index, const float* __restrict__ edge_attr,
    const unsigned short* __restrict__ node_f,
    const unsigned short* __restrict__ Wep, const float* __restrict__ be,
    const unsigned short* __restrict__ W1p, const float* __restrict__ b1,
    const unsigned short* __restrict__ W2p, const float* __restrict__ b2,
    const float* __restrict__ W3, const float* __restrict__ b3,
    float* __restrict__ out)
{
    // union buffer: phase1/2 comb [EPB][CSTR] (row-major), phase3 h1 [EPB][H1STR]
    __shared__ __align__(16) unsigned short smem[EPB * H1STR];
    __shared__ float out_lds[EPB];

    int tid = threadIdx.x;
    int wave = tid >> 6, lane = tid & 63;
    int lm = lane & 15, quad = lane >> 4;
    int e0 = blockIdx.x * EPB;

    if (tid < EPB) out_lds[tid] = 0.f;

    // ---- Phase 1a (issue): gather loads of node_f[src], node_f[dst] into regs ----
    // 8 threads per edge row; each thread owns a 16-short (32 B) chunk of src AND dst.
    int gi = tid >> 3, gp = tid & 7;
    uint4 gs0, gs1, gd0, gd1;
    {
        int e = e0 + gi;
        int ec = e < N_EDGES ? e : N_EDGES - 1;
        int s = edge_index[ec];
        int d = edge_index[N_EDGES + ec];
        const uint4* ps = (const uint4*)(node_f + s * HID + gp * 16);
        const uint4* pd = (const uint4*)(node_f + d * HID + gp * 16);
        gs0 = ps[0]; gs1 = ps[1];
        gd0 = pd[0]; gd1 = pd[1];
    }

    // ---- Phase 1b: edge_f^T = We^T @ edge_attr^T, cols [256,384) of comb ----
    // wave w: edge-tile nt = w%4, m-tiles mtg = (w/4)*4 + t (t=0..3)
    {
        int nt = wave & 3;
        int mbase = (wave >> 2) * 4;
        int erow = e0 + nt * 16 + lm;
        if (erow >= N_EDGES) erow = N_EDGES - 1;

        f4v zero = {0.f, 0.f, 0.f, 0.f};
        f4v acc[4];
        #pragma unroll
        for (int t = 0; t < 4; ++t) acc[t] = zero;

        for (int kb = 0; kb < 2; ++kb) {
            s8v b = load_a_f32(edge_attr, erow, EDGE_IN, kb * 32 + quad * 8);
            #pragma unroll
            for (int t = 0; t < 4; ++t) {
                s8v a = *(const s8v*)(Wep + (((kb * 8 + mbase + t) * 64 + lane) << 3));
                acc[t] = __builtin_amdgcn_mfma_f32_16x16x32_bf16(a, b, acc[t], 0, 0, 0);
            }
        }
        // write gather results (loads have had phase1b to complete)
        {
            uint4* cs = (uint4*)(smem + gi * CSTR + gp * 16);
            uint4* cd = (uint4*)(smem + gi * CSTR + 128 + gp * 16);
            cs[0] = gs0; cs[1] = gs1;
            cd[0] = gd0; cd[1] = gd1;
        }
        // edge_f epilogue: b64 writes, 4 consecutive cols per lane
        int edge = nt * 16 + lm;
        #pragma unroll
        for (int t = 0; t < 4; ++t) {
            int col = (mbase + t) * 16 + quad * 4;
            float4 bv = *(const float4*)(be + col);
            uint2 pk;
            pk.x = pk_bf16(fmaxf(acc[t][0] + bv.x, 0.f), fmaxf(acc[t][1] + bv.y, 0.f));
            pk.y = pk_bf16(fmaxf(acc[t][2] + bv.z, 0.f), fmaxf(acc[t][3] + bv.w, 0.f));
            *(uint2*)(smem + edge * CSTR + 256 + col) = pk;
        }
    }
    __syncthreads();

    // ---- Phase 2: h1^T = W1^T @ comb^T; wave w owns m-tiles w*4+t (t=0..3), all 4 edge-tiles ----
    f4v zero = {0.f, 0.f, 0.f, 0.f};
    f4v acc1[4][4];
    #pragma unroll
    for (int t = 0; t < 4; ++t)
        #pragma unroll
        for (int nt = 0; nt < 4; ++nt) acc1[t][nt] = zero;

    {
        const unsigned short* brow = smem + lm * CSTR + quad * 8;
        const unsigned short* wb = W1p + (((wave * 4) * 64 + lane) << 3);

        // preload kb=0 weights
        s8v afr[4];
        #pragma unroll
        for (int t = 0; t < 4; ++t) afr[t] = *(const s8v*)(wb + t * 512);

        #pragma unroll 1
        for (int kb = 0; kb < 12; ++kb) {
            s8v bfr[4];
            #pragma unroll
            for (int nt = 0; nt < 4; ++nt)
                bfr[nt] = *(const s8v*)(brow + kb * 32 + nt * (16 * CSTR));
            // Split-rotation weight prefetch for kb+1 (costs only 2 extra frags):
            // anx[0:2] issued BEFORE the MFMA burst; afr[2:4] reloaded AFTER the
            // burst (their old values are dead by then). At kb=11 this reads
            // past W1p end into W2p (workspace-adjacent by design, never used).
            const unsigned short* wn = wb + (kb + 1) * (32 * 64 * 8);
            s8v anx0 = *(const s8v*)(wn);
            s8v anx1 = *(const s8v*)(wn + 512);
            #pragma unroll
            for (int t = 0; t < 4; ++t)
                #pragma unroll
                for (int nt = 0; nt < 4; ++nt)
                    acc1[t][nt] = __builtin_amdgcn_mfma_f32_16x16x32_bf16(afr[t], bfr[nt], acc1[t][nt], 0, 0, 0);
            afr[0] = anx0;
            afr[1] = anx1;
            afr[2] = *(const s8v*)(wn + 1024);
            afr[3] = *(const s8v*)(wn + 1536);
        }
    }
    __syncthreads();  // everyone done reading comb before h1 overwrites it

    #pragma unroll
    for (int t = 0; t < 4; ++t) {
        int col = (wave * 4 + t) * 16 + quad * 4;
        float4 bv = *(const float4*)(b1 + col);
        #pragma unroll
        for (int nt = 0; nt < 4; ++nt) {
            int edge = nt * 16 + lm;
            uint2 pk;
            pk.x = pk_bf16(fmaxf(acc1[t][nt][0] + bv.x, 0.f), fmaxf(acc1[t][nt][1] + bv.y, 0.f));
            pk.y = pk_bf16(fmaxf(acc1[t][nt][2] + bv.z, 0.f), fmaxf(acc1[t][nt][3] + bv.w, 0.f));
            *(uint2*)(smem + edge * H1STR + col) = pk;
        }
    }
    __syncthreads();

    // ---- Phase 3: h2^T = W2^T @ h1^T; wave w owns m-tiles w*2+t (t=0..1), all 4 edge-tiles ----
    // acc1 is dead -> ample registers for a FULL 1-deep rotation (bnx[4]+anx[2]).
    f4v acc2[2][4];
    #pragma unroll
    for (int t = 0; t < 2; ++t)
        #pragma unroll
        for (int nt = 0; nt < 4; ++nt) acc2[t][nt] = zero;

    {
        const unsigned short* hrow = smem + lm * H1STR + quad * 8;
        const unsigned short* wb2 = W2p + (((wave * 2) * 64 + lane) << 3);

        s8v bfr[4], afr[2];
        #pragma unroll
        for (int nt = 0; nt < 4; ++nt)
            bfr[nt] = *(const s8v*)(hrow + nt * (16 * H1STR));
        afr[0] = *(const s8v*)(wb2);
        afr[1] = *(const s8v*)(wb2 + 512);

        #pragma unroll 1
        for (int kb = 0; kb < 16; ++kb) {
            int kbn = kb < 15 ? kb + 1 : 15;   // clamp keeps LDS & global reads in-bounds
            s8v bnx[4], anx[2];
            #pragma unroll
            for (int nt = 0; nt < 4; ++nt)
                bnx[nt] = *(const s8v*)(hrow + kbn * 32 + nt * (16 * H1STR));
            const unsigned short* wn = wb2 + kbn * (16 * 64 * 8);
            anx[0] = *(const s8v*)(wn);
            anx[1] = *(const s8v*)(wn + 512);
            #pragma unroll
            for (int t = 0; t < 2; ++t)
                #pragma unroll
                for (int nt = 0; nt < 4; ++nt)
                    acc2[t][nt] = __builtin_amdgcn_mfma_f32_16x16x32_bf16(afr[t], bfr[nt], acc2[t][nt], 0, 0, 0);
            #pragma unroll
            for (int nt = 0; nt < 4; ++nt) bfr[nt] = bnx[nt];
            afr[0] = anx[0];
            afr[1] = anx[1];
        }
    }

    // ---- Epilogue: relu(h2+b2) . W3 — per-lane partial over 8 h2-cols, quad-reduce ----
    {
        float4 b2v[2], w3v[2];
        #pragma unroll
        for (int t = 0; t < 2; ++t) {
            int col = (wave * 2 + t) * 16 + quad * 4;
            b2v[t] = *(const float4*)(b2 + col);
            w3v[t] = *(const float4*)(W3 + col);
        }
        #pragma unroll
        for (int nt = 0; nt < 4; ++nt) {
            float p = 0.f;
            #pragma unroll
            for (int t = 0; t < 2; ++t) {
                p += fmaxf(acc2[t][nt][0] + b2v[t].x, 0.f) * w3v[t].x;
                p += fmaxf(acc2[t][nt][1] + b2v[t].y, 0.f) * w3v[t].y;
                p += fmaxf(acc2[t][nt][2] + b2v[t].z, 0.f) * w3v[t].z;
                p += fmaxf(acc2[t][nt][3] + b2v[t].w, 0.f) * w3v[t].w;
            }
            p += __shfl_xor(p, 16);
            p += __shfl_xor(p, 32);
            if (quad == 0)
                atomicAdd(&out_lds[nt * 16 + lm], p);
        }
    }
    __syncthreads();

    if (tid < EPB) {
        int e = e0 + tid;
        if (e < N_EDGES) out[e] = out_lds[tid] + b3[0];
    }
}

extern "C" void kernel_launch(void* const* d_in, const int* in_sizes, int n_in,
                              void* d_out, int out_size, void* d_ws, size_t ws_size,
                              hipStream_t stream)
{
    const float* x          = (const float*)d_in[0];
    const int*   edge_index = (const int*)d_in[1];
    const float* edge_attr  = (const float*)d_in[2];
    const float* Wn = (const float*)d_in[3];
    const float* bn = (const float*)d_in[4];
    const float* We = (const float*)d_in[5];
    const float* be = (const float*)d_in[6];
    const float* W1 = (const float*)d_in[7];
    const float* b1 = (const float*)d_in[8];
    const float* W2 = (const float*)d_in[9];
    const float* b2 = (const float*)d_in[10];
    const float* W3 = (const float*)d_in[11];
    const float* b3 = (const float*)d_in[12];
    float* out = (float*)d_out;

    // Workspace layout (order matters: W2p must directly follow W1p so that
    // phase-2's guard-free kb=12 weight prefetch reads into W2p, not OOB).
    char* ws = (char*)d_ws;
    unsigned short* node_f = (unsigned short*)ws;                    // 12,800,000 B
    unsigned short* W1p = (unsigned short*)(ws + 12800000);          // 393,216 B
    unsigned short* W2p = (unsigned short*)(ws + 13193216);          // 262,144 B
    unsigned short* Wnp = (unsigned short*)(ws + 13455360);          // 32,768 B
    unsigned short* Wep = (unsigned short*)(ws + 13488128);          // 16,384 B

    pack_all<<<(PACK_TOTAL + 255) / 256, 256, 0, stream>>>(Wn, We, W1, W2, Wnp, Wep, W1p, W2p);

    node_feat_kernel<<<(N_NODES + 63) / 64, 256, 0, stream>>>(x, Wnp, bn, node_f);

    fused_edge_kernel<<<(N_EDGES + EPB - 1) / EPB, 512, 0, stream>>>(
        edge_index, edge_attr, node_f, Wep, be, W1p, b1, W2p, b2, W3, b3, out);
}

// Round 6
// 500.348 us; speedup vs baseline: 1.1683x; 1.1683x over previous
//
#include <hip/hip_runtime.h>
#include <hip/hip_bf16.h>
#include <stdint.h>

#define N_NODES 50000
#define N_EDGES 500000
#define NODE_IN 128
#define EDGE_IN 64
#define HID 128
#define K_H1 384   // 3*HID
#define N_H1 512   // 4*HID
#define N_H2 256   // 2*HID

#define EPB 64     // edges per block -> 2 independent blocks/CU (round-3: 1 blk/CU convoys)

typedef short s8v __attribute__((ext_vector_type(8)));   // 8 x bf16 bits (4 VGPR)
typedef float f4v __attribute__((ext_vector_type(4)));   // MFMA accumulator

// HW packed fp32->bf16 (v_cvt_pk_bf16_f32): low 16 bits = a, high = b
__device__ __forceinline__ unsigned int pk_bf16(float a, float b) {
    union { __hip_bfloat162 h; unsigned int u; } c;
    c.h = __float22bfloat162_rn(float2{a, b});
    return c.u;
}

// Load 8 consecutive fp32 from global, convert to a bf16 fragment.
// Fragment map (A and B identical): lane(lm,quad) holds [other=lm][k=quad*8+j].
__device__ __forceinline__ s8v load_a_f32(const float* __restrict__ base, int row, int ld, int koff) {
    const float4* p = (const float4*)(base + row * ld + koff);
    float4 x0 = p[0];
    float4 x1 = p[1];
    union { s8v v; unsigned int u[4]; } r;
    r.u[0] = pk_bf16(x0.x, x0.y);
    r.u[1] = pk_bf16(x0.z, x0.w);
    r.u[2] = pk_bf16(x1.x, x1.y);
    r.u[3] = pk_bf16(x1.z, x1.w);
    return r.v;
}

// Pack W (KxN row-major fp32) into fragment-ordered bf16:
// dst[(((kb*(N/16) + nt)*64 + lane)*8 + j] = W[kb*32 + (lane>>4)*8 + j][nt*16 + (lane&15)]
__device__ __forceinline__ void pack_one(const float* __restrict__ src, unsigned short* __restrict__ dst,
                                         int idx, int N) {
    int j = idx & 7;
    int lane = (idx >> 3) & 63;
    int rest = idx >> 9;
    int NT = N >> 4;
    int nt = rest % NT;
    int kb = rest / NT;
    int n = nt * 16 + (lane & 15);
    int k = kb * 32 + ((lane >> 4) << 3) + j;
    union { __hip_bfloat16 h; unsigned short s; } c;
    c.h = __float2bfloat16(src[k * N + n]);
    dst[idx] = c.s;
}

#define WN_ELEMS (NODE_IN * HID)          // 16384
#define WE_ELEMS (EDGE_IN * HID)          // 8192
#define W1_ELEMS (K_H1 * N_H1)            // 196608
#define W2_ELEMS (N_H1 * N_H2)            // 131072
#define PACK_TOTAL (WN_ELEMS + WE_ELEMS + W1_ELEMS + W2_ELEMS)

__global__ void pack_all(const float* __restrict__ Wn, const float* __restrict__ We,
                         const float* __restrict__ W1, const float* __restrict__ W2,
                         unsigned short* __restrict__ Wnp, unsigned short* __restrict__ Wep,
                         unsigned short* __restrict__ W1p, unsigned short* __restrict__ W2p) {
    int idx = blockIdx.x * blockDim.x + threadIdx.x;
    if (idx >= PACK_TOTAL) return;
    if (idx < WN_ELEMS) { pack_one(Wn, Wnp, idx, HID); return; }
    idx -= WN_ELEMS;
    if (idx < WE_ELEMS) { pack_one(We, Wep, idx, HID); return; }
    idx -= WE_ELEMS;
    if (idx < W1_ELEMS) { pack_one(W1, W1p, idx, N_H1); return; }
    idx -= W1_ELEMS;
    pack_one(W2, W2p, idx, N_H2);
}

// node_f^T formulation: D[m=hidcol][n=node] = Wn^T @ x^T.
__global__ __launch_bounds__(256, 4) void node_feat_kernel(
    const float* __restrict__ x, const unsigned short* __restrict__ Wnp,
    const float* __restrict__ bn, unsigned short* __restrict__ node_f)
{
    int tid = threadIdx.x;
    int wave = tid >> 6, lane = tid & 63;
    int lm = lane & 15, quad = lane >> 4;
    int row0 = blockIdx.x * 64;
    int node = row0 + wave * 16 + lm;
    int nodec = node < N_NODES ? node : N_NODES - 1;

    f4v zero = {0.f, 0.f, 0.f, 0.f};
    f4v acc[8];
    #pragma unroll
    for (int mt = 0; mt < 8; ++mt) acc[mt] = zero;

    for (int kb = 0; kb < 4; ++kb) {
        s8v b = load_a_f32(x, nodec, NODE_IN, kb * 32 + quad * 8);
        #pragma unroll
        for (int mt = 0; mt < 8; ++mt) {
            s8v a = *(const s8v*)(Wnp + (((kb * 8 + mt) * 64 + lane) << 3));
            acc[mt] = __builtin_amdgcn_mfma_f32_16x16x32_bf16(a, b, acc[mt], 0, 0, 0);
        }
    }

    if (node < N_NODES) {
        #pragma unroll
        for (int mt = 0; mt < 8; ++mt) {
            float4 bv = *(const float4*)(bn + mt * 16 + quad * 4);
            uint2 pk;
            pk.x = pk_bf16(fmaxf(acc[mt][0] + bv.x, 0.f), fmaxf(acc[mt][1] + bv.y, 0.f));
            pk.y = pk_bf16(fmaxf(acc[mt][2] + bv.z, 0.f), fmaxf(acc[mt][3] + bv.w, 0.f));
            *(uint2*)(node_f + node * HID + mt * 16 + quad * 4) = pk;
        }
    }
}

// Fused per-edge pipeline (all GEMMs in swapped D=W^T@X^T form).
// block: 512 threads (8 waves), 64 edges. LDS ~66.8 KB -> 2 blocks/CU.
//
// ROUND-5/6 STRUCTURE (resubmitted after infra failure): per-wave 1-deep
// weight double-buffer with COUNTED vmcnt (T3/T4-minimal). Rounds 0/1: full
// prefetch spilled (reg overflow). Round 4: half-prefetch loaded AFTER the
// burst -> zero latency cover, -24%. Fix: hand-unrolled x2 kb-loop with
// NAMED even/odd A-buffers; next-kb loads issue BEFORE the burst; inline-asm
// `s_waitcnt vmcnt(N)` (N = loads just issued) retires exactly the consumed
// buffer, issued one full iteration earlier. sched_barrier(0) after each
// wait stops MFMA hoisting (guide rule #18).
// Registers: ph2 acc 64 AGPR + aev/aod/bfr 48 arch + misc; ph3 comfortable.
// Tripwires: WRITE_SIZE ~2 MB, VGPR <= 64.
#define CSTR 392   // comb row stride (shorts, 384 + 8 pad)
#define H1STR 520  // h1 row stride (shorts, 512 + 8 pad)

__global__ __launch_bounds__(512, 4) void fused_edge_kernel(
    const int* __restrict__ edge_index, const float* __restrict__ edge_attr,
    const unsigned short* __restrict__ node_f,
    const unsigned short* __restrict__ Wep, const float* __restrict__ be,
    const unsigned short* __restrict__ W1p, const float* __restrict__ b1,
    const unsigned short* __restrict__ W2p, const float* __restrict__ b2,
    const float* __restrict__ W3, const float* __restrict__ b3,
    float* __restrict__ out)
{
    // union buffer: phase1/2 comb [EPB][CSTR] (row-major), phase3 h1 [EPB][H1STR]
    __shared__ __align__(16) unsigned short smem[EPB * H1STR];
    __shared__ float out_lds[EPB];

    int tid = threadIdx.x;
    int wave = tid >> 6, lane = tid & 63;
    int lm = lane & 15, quad = lane >> 4;
    int e0 = blockIdx.x * EPB;

    if (tid < EPB) out_lds[tid] = 0.f;

    // ---- Phase 1a (issue): gather loads of node_f[src], node_f[dst] into regs ----
    int gi = tid >> 3, gp = tid & 7;
    uint4 gs0, gs1, gd0, gd1;
    {
        int e = e0 + gi;
        int ec = e < N_EDGES ? e : N_EDGES - 1;
        int s = edge_index[ec];
        int d = edge_index[N_EDGES + ec];
        const uint4* ps = (const uint4*)(node_f + s * HID + gp * 16);
        const uint4* pd = (const uint4*)(node_f + d * HID + gp * 16);
        gs0 = ps[0]; gs1 = ps[1];
        gd0 = pd[0]; gd1 = pd[1];
    }

    // ---- Phase 1b: edge_f^T = We^T @ edge_attr^T, cols [256,384) of comb ----
    {
        int nt = wave & 3;
        int mbase = (wave >> 2) * 4;
        int erow = e0 + nt * 16 + lm;
        if (erow >= N_EDGES) erow = N_EDGES - 1;

        f4v zero = {0.f, 0.f, 0.f, 0.f};
        f4v acc[4];
        #pragma unroll
        for (int t = 0; t < 4; ++t) acc[t] = zero;

        for (int kb = 0; kb < 2; ++kb) {
            s8v b = load_a_f32(edge_attr, erow, EDGE_IN, kb * 32 + quad * 8);
            #pragma unroll
            for (int t = 0; t < 4; ++t) {
                s8v a = *(const s8v*)(Wep + (((kb * 8 + mbase + t) * 64 + lane) << 3));
                acc[t] = __builtin_amdgcn_mfma_f32_16x16x32_bf16(a, b, acc[t], 0, 0, 0);
            }
        }
        {
            uint4* cs = (uint4*)(smem + gi * CSTR + gp * 16);
            uint4* cd = (uint4*)(smem + gi * CSTR + 128 + gp * 16);
            cs[0] = gs0; cs[1] = gs1;
            cd[0] = gd0; cd[1] = gd1;
        }
        int edge = nt * 16 + lm;
        #pragma unroll
        for (int t = 0; t < 4; ++t) {
            int col = (mbase + t) * 16 + quad * 4;
            float4 bv = *(const float4*)(be + col);
            uint2 pk;
            pk.x = pk_bf16(fmaxf(acc[t][0] + bv.x, 0.f), fmaxf(acc[t][1] + bv.y, 0.f));
            pk.y = pk_bf16(fmaxf(acc[t][2] + bv.z, 0.f), fmaxf(acc[t][3] + bv.w, 0.f));
            *(uint2*)(smem + edge * CSTR + 256 + col) = pk;
        }
    }

    // Phase-2 weight prologue: issue A(kb=0) BEFORE the barrier. The barrier's
    // implicit vmcnt(0) drain makes aev ready at loop entry (free cover) and
    // zeroes the vmem counter so in-loop counting is exact.
    const unsigned short* wb1 = W1p + (((wave * 4) * 64 + lane) << 3);
    s8v aev[4], aod[4];
    #pragma unroll
    for (int t = 0; t < 4; ++t) aev[t] = *(const s8v*)(wb1 + t * 512);

    __syncthreads();

    // ---- Phase 2: h1^T = W1^T @ comb^T; wave w owns m-tiles w*4+t, all 4 edge-tiles ----
    // Per step: issue next-kb weights (4 loads) -> ds_read bfr -> waitcnt
    // vmcnt(4) [allow the 4 just-issued; retires the buffer issued last step]
    // lgkmcnt(0) -> 16 MFMA. Weight latency cover = one full kb step.
    f4v zero = {0.f, 0.f, 0.f, 0.f};
    f4v acc1[4][4];
    #pragma unroll
    for (int t = 0; t < 4; ++t)
        #pragma unroll
        for (int nt = 0; nt < 4; ++nt) acc1[t][nt] = zero;

    {
        const unsigned short* brp = smem + lm * CSTR + quad * 8;  // even: +0, odd: +32, +=64/pair
        const unsigned short* wnext = wb1 + 16384;                // A(kb+1) block, +=16384/step

        s8v bfr[4];
        #pragma unroll 1
        for (int kb = 0; kb < 12; kb += 2) {
            // --- even step: consume aev(kb), prefetch aod = A(kb+1) ---
            #pragma unroll
            for (int t = 0; t < 4; ++t) aod[t] = *(const s8v*)(wnext + t * 512);
            wnext += 16384;
            #pragma unroll
            for (int nt = 0; nt < 4; ++nt)
                bfr[nt] = *(const s8v*)(brp + nt * (16 * CSTR));
            asm volatile("s_waitcnt vmcnt(4) lgkmcnt(0)" ::: "memory");
            __builtin_amdgcn_sched_barrier(0);
            #pragma unroll
            for (int t = 0; t < 4; ++t)
                #pragma unroll
                for (int nt = 0; nt < 4; ++nt)
                    acc1[t][nt] = __builtin_amdgcn_mfma_f32_16x16x32_bf16(aev[t], bfr[nt], acc1[t][nt], 0, 0, 0);
            // --- odd step: consume aod(kb+1), prefetch aev = A(kb+2) ---
            // (at kb=10 this loads A(12), 0..2KB past W1p end -> lands in W2p,
            //  workspace-adjacent by design, value never used)
            #pragma unroll
            for (int t = 0; t < 4; ++t) aev[t] = *(const s8v*)(wnext + t * 512);
            wnext += 16384;
            #pragma unroll
            for (int nt = 0; nt < 4; ++nt)
                bfr[nt] = *(const s8v*)(brp + 32 + nt * (16 * CSTR));
            asm volatile("s_waitcnt vmcnt(4) lgkmcnt(0)" ::: "memory");
            __builtin_amdgcn_sched_barrier(0);
            #pragma unroll
            for (int t = 0; t < 4; ++t)
                #pragma unroll
                for (int nt = 0; nt < 4; ++nt)
                    acc1[t][nt] = __builtin_amdgcn_mfma_f32_16x16x32_bf16(aod[t], bfr[nt], acc1[t][nt], 0, 0, 0);
            brp += 64;
        }
    }
    __syncthreads();  // everyone done reading comb before h1 overwrites it
                      // (also drains the 4 junk A(12) loads -> counter clean)

    #pragma unroll
    for (int t = 0; t < 4; ++t) {
        int col = (wave * 4 + t) * 16 + quad * 4;
        float4 bv = *(const float4*)(b1 + col);
        #pragma unroll
        for (int nt = 0; nt < 4; ++nt) {
            int edge = nt * 16 + lm;
            uint2 pk;
            pk.x = pk_bf16(fmaxf(acc1[t][nt][0] + bv.x, 0.f), fmaxf(acc1[t][nt][1] + bv.y, 0.f));
            pk.y = pk_bf16(fmaxf(acc1[t][nt][2] + bv.z, 0.f), fmaxf(acc1[t][nt][3] + bv.w, 0.f));
            *(uint2*)(smem + edge * H1STR + col) = pk;
        }
    }

    // Phase-3 weight prologue: issue A(0) before the h1-publish barrier.
    const unsigned short* wb2 = W2p + (((wave * 2) * 64 + lane) << 3);
    s8v a3ev[2], a3od[2];
    a3ev[0] = *(const s8v*)(wb2);
    a3ev[1] = *(const s8v*)(wb2 + 512);

    __syncthreads();

    // ---- Phase 3: h2^T = W2^T @ h1^T; wave w owns m-tiles w*2+t, all 4 edge-tiles ----
    // Same counted-vmcnt pattern, 2 weight loads/step -> vmcnt(2).
    f4v acc2[2][4];
    #pragma unroll
    for (int t = 0; t < 2; ++t)
        #pragma unroll
        for (int nt = 0; nt < 4; ++nt) acc2[t][nt] = zero;

    {
        const unsigned short* hrp = smem + lm * H1STR + quad * 8;  // even: +0, odd: +32, +=64/pair
        const unsigned short* wnext = wb2 + 8192;                  // A(kb+1), +=8192/step

        s8v bfr[4];
        #pragma unroll 1
        for (int kb = 0; kb < 16; kb += 2) {
            // --- even: consume a3ev(kb), prefetch a3od = A(kb+1) ---
            a3od[0] = *(const s8v*)(wnext);
            a3od[1] = *(const s8v*)(wnext + 512);
            wnext += 8192;
            #pragma unroll
            for (int nt = 0; nt < 4; ++nt)
                bfr[nt] = *(const s8v*)(hrp + nt * (16 * H1STR));
            asm volatile("s_waitcnt vmcnt(2) lgkmcnt(0)" ::: "memory");
            __builtin_amdgcn_sched_barrier(0);
            #pragma unroll
            for (int t = 0; t < 2; ++t)
                #pragma unroll
                for (int nt = 0; nt < 4; ++nt)
                    acc2[t][nt] = __builtin_amdgcn_mfma_f32_16x16x32_bf16(a3ev[t], bfr[nt], acc2[t][nt], 0, 0, 0);
            // --- odd: consume a3od(kb+1), prefetch a3ev = A(kb+2) ---
            // (at kb=14 this loads A(16) = exactly W2p end -> lands in Wnp, unused)
            a3ev[0] = *(const s8v*)(wnext);
            a3ev[1] = *(const s8v*)(wnext + 512);
            wnext += 8192;
            #pragma unroll
            for (int nt = 0; nt < 4; ++nt)
                bfr[nt] = *(const s8v*)(hrp + 32 + nt * (16 * H1STR));
            asm volatile("s_waitcnt vmcnt(2) lgkmcnt(0)" ::: "memory");
            __builtin_amdgcn_sched_barrier(0);
            #pragma unroll
            for (int t = 0; t < 2; ++t)
                #pragma unroll
                for (int nt = 0; nt < 4; ++nt)
                    acc2[t][nt] = __builtin_amdgcn_mfma_f32_16x16x32_bf16(a3od[t], bfr[nt], acc2[t][nt], 0, 0, 0);
            hrp += 64;
        }
    }

    // ---- Epilogue: relu(h2+b2) . W3 — per-lane partial over 8 h2-cols, quad-reduce ----
    {
        float4 b2v[2], w3v[2];
        #pragma unroll
        for (int t = 0; t < 2; ++t) {
            int col = (wave * 2 + t) * 16 + quad * 4;
            b2v[t] = *(const float4*)(b2 + col);
            w3v[t] = *(const float4*)(W3 + col);
        }
        #pragma unroll
        for (int nt = 0; nt < 4; ++nt) {
            float p = 0.f;
            #pragma unroll
            for (int t = 0; t < 2; ++t) {
                p += fmaxf(acc2[t][nt][0] + b2v[t].x, 0.f) * w3v[t].x;
                p += fmaxf(acc2[t][nt][1] + b2v[t].y, 0.f) * w3v[t].y;
                p += fmaxf(acc2[t][nt][2] + b2v[t].z, 0.f) * w3v[t].z;
                p += fmaxf(acc2[t][nt][3] + b2v[t].w, 0.f) * w3v[t].w;
            }
            p += __shfl_xor(p, 16);
            p += __shfl_xor(p, 32);
            if (quad == 0)
                atomicAdd(&out_lds[nt * 16 + lm], p);
        }
    }
    __syncthreads();

    if (tid < EPB) {
        int e = e0 + tid;
        if (e < N_EDGES) out[e] = out_lds[tid] + b3[0];
    }
}

extern "C" void kernel_launch(void* const* d_in, const int* in_sizes, int n_in,
                              void* d_out, int out_size, void* d_ws, size_t ws_size,
                              hipStream_t stream)
{
    const float* x          = (const float*)d_in[0];
    const int*   edge_index = (const int*)d_in[1];
    const float* edge_attr  = (const float*)d_in[2];
    const float* Wn = (const float*)d_in[3];
    const float* bn = (const float*)d_in[4];
    const float* We = (const float*)d_in[5];
    const float* be = (const float*)d_in[6];
    const float* W1 = (const float*)d_in[7];
    const float* b1 = (const float*)d_in[8];
    const float* W2 = (const float*)d_in[9];
    const float* b2 = (const float*)d_in[10];
    const float* W3 = (const float*)d_in[11];
    const float* b3 = (const float*)d_in[12];
    float* out = (float*)d_out;

    // Workspace layout (order matters: W2p directly follows W1p so phase-2's
    // guard-free A(12) prefetch lands in W2p; Wnp follows W2p for phase-3's
    // A(16) prefetch).
    char* ws = (char*)d_ws;
    unsigned short* node_f = (unsigned short*)ws;                    // 12,800,000 B
    unsigned short* W1p = (unsigned short*)(ws + 12800000);          // 393,216 B
    unsigned short* W2p = (unsigned short*)(ws + 13193216);          // 262,144 B
    unsigned short* Wnp = (unsigned short*)(ws + 13455360);          // 32,768 B
    unsigned short* Wep = (unsigned short*)(ws + 13488128);          // 16,384 B

    pack_all<<<(PACK_TOTAL + 255) / 256, 256, 0, stream>>>(Wn, We, W1, W2, Wnp, Wep, W1p, W2p);

    node_feat_kernel<<<(N_NODES + 63) / 64, 256, 0, stream>>>(x, Wnp, bn, node_f);

    fused_edge_kernel<<<(N_EDGES + EPB - 1) / EPB, 512, 0, stream>>>(
        edge_index, edge_attr, node_f, Wep, be, W1p, b1, W2p, b2, W3, b3, out);
}